// Round 10
// baseline (344.515 us; speedup 1.0000x reference)
//
#include <hip/hip_runtime.h>
#include <stdint.h>

// Problem constants (B,S,D fixed by the reference)
#define B_  4
#define S_  2048
#define D_  1024
#define DK_ 1024
#define DV_ 1024

typedef __attribute__((ext_vector_type(8)))  short short8;    // 8 bf16 = 4 VGPRs (MFMA A/B frag)
typedef __attribute__((ext_vector_type(16))) float floatx16;  // 32x32 MFMA C/D frag

// async global->LDS DMA, 16B per lane, wave-uniform LDS base (lane scatters +lane*16B)
#define ASYNC16(gsrc, ldst)                                                        \
  __builtin_amdgcn_global_load_lds(                                                \
      (const __attribute__((address_space(1))) unsigned int*)(gsrc),               \
      (__attribute__((address_space(3))) unsigned int*)(ldst), 16, 0, 0)

#define WAITVM(N) asm volatile("s_waitcnt vmcnt(" #N ")" ::: "memory")

// round-to-nearest-even fp32 -> bf16
__device__ __forceinline__ unsigned short f2bf(float f) {
  union { float f; uint32_t u; } v; v.f = f;
  uint32_t r = v.u + 0x7fffu + ((v.u >> 16) & 1u);
  return (unsigned short)(r >> 16);
}

// ---------------- prep: fp32->bf16 for q/k/v  +  W^T (bf16), one dispatch ----------------
__global__ __launch_bounds__(256)
void prep(const float* __restrict__ q, const float* __restrict__ k, const float* __restrict__ v,
          const float* __restrict__ W0, const float* __restrict__ W1, const float* __restrict__ W2,
          unsigned short* __restrict__ qkv, unsigned short* __restrict__ WT) {
  const int bid = blockIdx.x, tid = threadIdx.x;
  if (bid < 12288) {
    const int t  = bid >> 12;         // tensor 0..2
    const int cb = bid & 4095;        // chunk within tensor
    const float* in = (t == 0) ? q : (t == 1) ? k : v;
    unsigned short* o = qkv + (long)t * ((long)B_ * S_ * D_);
    const int i0 = cb * 512 + tid;    // float4 index (512 per block)
    float4 v0 = ((const float4*)in)[i0];
    float4 v1 = ((const float4*)in)[i0 + 256];
    ushort4 u0, u1;
    u0.x = f2bf(v0.x); u0.y = f2bf(v0.y); u0.z = f2bf(v0.z); u0.w = f2bf(v0.w);
    u1.x = f2bf(v1.x); u1.y = f2bf(v1.y); u1.z = f2bf(v1.z); u1.w = f2bf(v1.w);
    ((ushort4*)o)[i0] = u0;
    ((ushort4*)o)[i0 + 256] = u1;
  } else {
    const int b2 = bid - 12288;
    const int w  = b2 >> 10;          // weight 0..2
    const int tl = b2 & 1023;         // 32x32 tile id
    const float* in = (w == 0) ? W0 : (w == 1) ? W1 : W2;
    unsigned short* o = WT + (long)w * D_ * DK_;
    __shared__ float tile[32][33];
    const int bx = (tl & 31) * 32, by = (tl >> 5) * 32;
    const int tx = tid & 31, ty = tid >> 5;
    for (int r = ty; r < 32; r += 8)
      tile[r][tx] = in[(long)(by + r) * DK_ + bx + tx];
    __syncthreads();
    for (int r = ty; r < 32; r += 8)
      o[(long)(bx + r) * D_ + by + tx] = f2bf(tile[tx][r]);
  }
}

__device__ __forceinline__ void storeC(float* p, float v)          { *p = v; }
__device__ __forceinline__ void storeC(unsigned short* p, float v) { *p = f2bf(v); }

// ---------------- combine: out = (out + P) / rowsum, rowsum = sum of 32 partials ----------------
__global__ __launch_bounds__(256)
void combine(float* __restrict__ out, const float* __restrict__ P,
             const float* __restrict__ rsp) {
  __shared__ float sinv;
  const int row = blockIdx.x;
  const int tid = threadIdx.x;
  if (tid < 32) {
    float s = rsp[(long)tid * (B_ * S_) + row];
#pragma unroll
    for (int m = 1; m < 32; m <<= 1) s += __shfl_xor(s, m, 64);
    if (tid == 0) sinv = 1.0f / s;
  }
  __syncthreads();
  const float inv = sinv;
  const long k = (long)row * 256 + tid;          // float4 index (row covers DV_=1024 floats)
  float4 a = ((const float4*)out)[k];
  float4 b = ((const float4*)P)[k];
  float4 o;
  o.x = (a.x + b.x) * inv; o.y = (a.y + b.y) * inv;
  o.z = (a.z + b.z) * inv; o.w = (a.w + b.w) * inv;
  ((float4*)out)[k] = o;
}

// ---------------- bf16 BT GEMM, BMx256 tile, 8 waves, 4-buf ring depth-3 lookahead ----------------
// ROUND 16.  r9 post-mortem: dispatch-id mod-16 analysis shows ALL top-5 rows were QKV
//   (FETCH 74 / WRITE 49 = Q+K+V 48MB signature); scores/PV are BELOW the 85.6us cutoff.
//   The r8 "identical loop 2x slower" anomaly was a misattribution artifact.  QKV's 86us =
//   384 blocks at 1 block/CU = 2 rounds (256+128), second round HALF-EMPTY; t_block=43us
//   ~= 800 TF-equiv, within 6% of the guide's best plain-HIP number for this shape class
//   (m248v2: 848 TF at 256^2/K=1024).  Fix = grid packing, not schedule: QKV moves to
//   BM=128 tiles -> 12x64 = 768 blocks = exactly 3 full rounds of half-size blocks.
// BM template param (128 or 256): per-wave rows BM/2 (2 M-waves x 4 N-waves), IR=BM/64
//   acc row-frags, A-staging BM/8 rows per wave = nA=BM/128 DMAs per tile; per-tile DMA
//   count DPT=nA+2 -> counted-vmcnt constants 2*DPT / DPT / 0 via if constexpr.
// K-loop schedule otherwise UNCHANGED from r9 (passed, 341.9us).
// Swizzle (r6-verified): LDS[row][q16] = global[row][q16 ^ ((row>>1)&3)] within 64B line;
//   read off=((s*2+hi)^((lm>>1)&3))*8.  A/B frag (32x32x16): m(n)=lane&31, k-chunk=s*2+hi.
// C/D (m74/m101 verified): col=lane&31, row=(reg&3)+8*(reg>>2)+4*(lane>>5).
// NOUT=3: fused QKV (n0g selects A/C/bias).  sel==2 stores V transposed into Vt[B][DV][S].
// MODE: 0 plain store (+bias if non-null); 1 store exp(val*scale) + partial row sums to rsp.
// KSPL: K-split; kh=bzi&1 selects K-half; kh==1 redirects C to C1 (separate partial buffer).
template <typename OutT, int NOUT, int MODE, int KSPL, int BM>
__global__ __launch_bounds__(512, 2)
void gemm_bt256(const unsigned short* __restrict__ A0, const unsigned short* __restrict__ A1,
                const unsigned short* __restrict__ A2, const unsigned short* __restrict__ Bm,
                OutT* __restrict__ C0, OutT* __restrict__ C1, OutT* __restrict__ C2,
                const float* __restrict__ b0, const float* __restrict__ b1,
                const float* __restrict__ b2, float* __restrict__ rsp,
                int N, int K, int lda, int ldb, long sA, long sB, long sC, float scale) {
  constexpr int IR = BM / 64;          // acc row-frags per wave (256->4, 128->2)
  constexpr int IH = IR / 2;           // row-frags per phase
  constexpr int nA = BM / 128;         // A DMAs per wave per tile (2 or 1)
  __shared__ __align__(16) unsigned short As[4][BM * 32];    // 4-ring
  __shared__ __align__(16) unsigned short Bs[4][256 * 32];
  const int tid  = threadIdx.x;
  const int lane = tid & 63, wave = tid >> 6;     // 8 waves
  const int wm = (wave >> 2) * (BM / 2);          // 2 M-waves
  const int wn = (wave & 3) * 64;                 // 4 N-waves
  const int lm = lane & 31;
  const int hi = lane >> 5;

  // ---- bijective XCD-chunk remap (8 XCDs; every grid here has total %8 == 0) ----
  const int gx = gridDim.x, gy = gridDim.y;
  const int T  = gx * gy * (int)gridDim.z;
  const int l  = blockIdx.x + gx * (blockIdx.y + gy * blockIdx.z);
  const int l2 = (l & 7) * (T >> 3) + (l >> 3);
  const int bxi = l2 % gx;
  const int byi = (l2 / gx) % gy;
  const int bzi = l2 / (gx * gy);

  const int  kh = (KSPL > 1) ? (bzi & (KSPL - 1)) : 0;
  const long zb = (KSPL > 1) ? (bzi >> 1) : bzi;
  const int m0  = byi * BM;
  const int n0g = bxi * 256;

  const unsigned short* A = A0;
  OutT* C = C0;
  const float* bias = b0;
  int n0 = n0g, sel = 0;
  if (NOUT == 3) {
    sel = n0g >> 10;
    n0 = n0g & 1023;
    if (sel == 1)      { A = A1; C = C1; bias = b1; }
    else if (sel == 2) { A = A2; C = C2; bias = b2; }
  }
  if (KSPL > 1 && kh) C = C1;          // K-half 1 writes its own partial buffer
  A += zb * sA + (long)kh * K;
  const unsigned short* Bp = Bm + zb * sB + (long)kh * K;
  C += zb * sC;

  // ---- staging: wave w owns A rows [BM/8*w, +BM/8), B rows [32w, 32w+32) ----
  const int rr = lane >> 2;
  const int cc = (((lane & 3) ^ ((lane >> 3) & 3)) * 8);    // 64B-line XOR swizzle on source
  const unsigned short* gA0 = A  + (long)(m0  + (BM / 8) * wave + rr) * lda + cc;
  const unsigned short* gA1 = gA0 + 16 * (long)lda;          // used only if nA==2
  const unsigned short* gB0 = Bp + (long)(n0g + 32 * wave + rr) * ldb + cc;
  const unsigned short* gB1 = gB0 + 16 * (long)ldb;
  const int aoff = wave * (BM * 4);                          // (BM/8)*32 shorts per wave
  const int boff = wave * 1024;

  floatx16 acc[IR][2] = {};
  const int sw = (lm >> 1) & 3;

  const int nt = K >> 5;                           // BK=32 tiles (>= 4 for all our shapes)

  // ---- prologue: stage tiles 0,1,2 -> bufs 0,1,2; retire tile 0's DPT ----
#pragma unroll
  for (int pt = 0; pt < 3; pt++) {
    ASYNC16(gA0, &As[pt][aoff]);
    if (nA == 2) ASYNC16(gA1, &As[pt][aoff + 512]);
    ASYNC16(gB0, &Bs[pt][boff]); ASYNC16(gB1, &Bs[pt][boff + 512]);
    gA0 += 32; gA1 += 32; gB0 += 32; gB1 += 32;
  }
  if constexpr (BM == 256) { WAITVM(8); } else { WAITVM(6); }
  __builtin_amdgcn_s_barrier();

  // ---- main loop: 2 phases per BK=32 tile, 4-buf ring, depth-3 lookahead ----
  for (int t = 0; t < nt; t++) {
    const int bc = t & 3;                          // buf of tile t
    const int bs = (t + 3) & 3;                    // buf of tile t+3
    const bool pre = (t + 3 < nt);

    // ---- phase 0: af(i < IH) + bf(all); stage A(t+3) ----
    short8 af[IH][2], bf[2][2];
#pragma unroll
    for (int i = 0; i < IH; i++)
#pragma unroll
      for (int s = 0; s < 2; s++)
        af[i][s] = *(const short8*)&As[bc][(wm + i * 32 + lm) * 32 + (((s * 2 + hi) ^ sw) * 8)];
#pragma unroll
    for (int j = 0; j < 2; j++)
#pragma unroll
      for (int s = 0; s < 2; s++)
        bf[j][s] = *(const short8*)&Bs[bc][(wn + j * 32 + lm) * 32 + (((s * 2 + hi) ^ sw) * 8)];
    if (pre) {
      ASYNC16(gA0, &As[bs][aoff]);
      if (nA == 2) ASYNC16(gA1, &As[bs][aoff + 512]);
      gA0 += 32; gA1 += 32;
    }
    __builtin_amdgcn_s_barrier();
    asm volatile("s_waitcnt lgkmcnt(0)" ::: "memory");
    __builtin_amdgcn_s_setprio(1);
#pragma unroll
    for (int s = 0; s < 2; s++)
#pragma unroll
      for (int i = 0; i < IH; i++)
#pragma unroll
        for (int j = 0; j < 2; j++)
          acc[i][j] = __builtin_amdgcn_mfma_f32_32x32x16_bf16(af[i][s], bf[j][s], acc[i][j], 0, 0, 0);
    __builtin_amdgcn_s_setprio(0);
    __builtin_amdgcn_s_barrier();

    // ---- phase 1: af2(i in [IH,IR)), bf carried in regs; stage B(t+3) ----
    short8 af2[IH][2];
#pragma unroll
    for (int i = 0; i < IH; i++)
#pragma unroll
      for (int s = 0; s < 2; s++)
        af2[i][s] = *(const short8*)&As[bc][(wm + (IH + i) * 32 + lm) * 32 + (((s * 2 + hi) ^ sw) * 8)];
    if (pre) {
      ASYNC16(gB0, &Bs[bs][boff]); ASYNC16(gB1, &Bs[bs][boff + 512]);
      gB0 += 32; gB1 += 32;
    }
    __builtin_amdgcn_s_barrier();
    asm volatile("s_waitcnt lgkmcnt(0)" ::: "memory");
    __builtin_amdgcn_s_setprio(1);
#pragma unroll
    for (int s = 0; s < 2; s++)
#pragma unroll
      for (int i = 0; i < IH; i++)
#pragma unroll
        for (int j = 0; j < 2; j++)
          acc[IH + i][j] = __builtin_amdgcn_mfma_f32_32x32x16_bf16(af2[i][s], bf[j][s], acc[IH + i][j], 0, 0, 0);
    __builtin_amdgcn_s_setprio(0);
    // retire tile t+1's DMAs; keep younger tiles in flight (counted, never 0 while staging)
    if (t + 3 < nt)      { if constexpr (BM == 256) { WAITVM(8); } else { WAITVM(6); } }
    else if (t + 2 < nt) { if constexpr (BM == 256) { WAITVM(4); } else { WAITVM(3); } }
    else                 { WAITVM(0); }
    __builtin_amdgcn_s_barrier();
  }

  // ---- epilogue: C/D col=lane&31, row=(r&3)+8*(r>>2)+4*hi ----
  if (NOUT == 3 && sel == 2) {
    // V output, stored transposed into Vt[B][DV][S]
    unsigned short* Vt = (unsigned short*)C;
    const int b = m0 >> 11;              // batch (2048 rows per batch; BM | 2048)
    const int sbase = (m0 & 2047);
#pragma unroll
    for (int i = 0; i < IR; i++) {
      const int srowb = sbase + wm + i * 32 + (hi << 2);
#pragma unroll
      for (int j = 0; j < 2; j++) {
        const int col = n0 + wn + j * 32 + lm;
        const float bv = bias[col];
        unsigned short* vp = Vt + ((long)b * DV_ + col) * S_ + srowb;
#pragma unroll
        for (int g = 0; g < 4; g++) {
          ushort4 u;
          u.x = f2bf(acc[i][j][4 * g + 0] + bv);
          u.y = f2bf(acc[i][j][4 * g + 1] + bv);
          u.z = f2bf(acc[i][j][4 * g + 2] + bv);
          u.w = f2bf(acc[i][j][4 * g + 3] + bv);
          *(ushort4*)(vp + 8 * g) = u;
        }
      }
    }
  } else if (MODE == 1) {
    // scores: store U = exp(score*scale); per-(bxi,wave) partial row sums -> rsp (plain stores)
#pragma unroll
    for (int i = 0; i < IR; i++) {
#pragma unroll
      for (int r = 0; r < 16; r++) {
        const int row = m0 + wm + i * 32 + (r & 3) + ((r >> 2) << 3) + (hi << 2);
        float sum2 = 0.f;
#pragma unroll
        for (int j = 0; j < 2; j++) {
          const int col = n0 + wn + j * 32 + lm;
          float e = __expf(acc[i][j][r] * scale);
          storeC(C + (long)row * N + col, e);
          sum2 += e;
        }
#pragma unroll
        for (int msk = 1; msk < 32; msk <<= 1) sum2 += __shfl_xor(sum2, msk, 64);
        if ((lane & 31) == 0)
          rsp[(long)(bxi * 4 + (wave & 3)) * (B_ * S_) + zb * S_ + row] = sum2;
      }
    }
  } else {
#pragma unroll
    for (int i = 0; i < IR; i++) {
#pragma unroll
      for (int j = 0; j < 2; j++) {
        const int col = n0 + wn + j * 32 + lm;
        const float bv = bias ? bias[col] : 0.f;
#pragma unroll
        for (int r = 0; r < 16; r++) {
          const int rl = wm + i * 32 + (r & 3) + ((r >> 2) << 3) + (hi << 2);
          storeC(C + (long)(m0 + rl) * N + col, acc[i][j][r] * scale + bv);
        }
      }
    }
  }
}

extern "C" void kernel_launch(void* const* d_in, const int* in_sizes, int n_in,
                              void* d_out, int out_size, void* d_ws, size_t ws_size,
                              hipStream_t stream) {
  const float* q_in = (const float*)d_in[0];
  const float* k_in = (const float*)d_in[1];
  const float* v_in = (const float*)d_in[2];
  const float* Wq   = (const float*)d_in[3];
  const float* bq   = (const float*)d_in[4];
  const float* Wk   = (const float*)d_in[5];
  const float* bk   = (const float*)d_in[6];
  const float* Wv   = (const float*)d_in[7];
  const float* bv   = (const float*)d_in[8];
  float* out = (float*)d_out;

  // ---- workspace layout ----
  // U (bf16 scores, 33.5MB) overlays dead qb+kb after QKV;
  // rowsumP (32 x B*S fp32 = 1MB) overlays dead vb after QKV;
  // P (fp32 PV half-1 partial, 33.5MB) overlays dead Qb+Kb after scores.
  char* ws = (char*)d_ws;
  const long nX = (long)B_ * S_ * D_;   // 8388608 elems
  const long nW = (long)D_ * DK_;       // 1048576
  unsigned short* qb  = (unsigned short*)(ws);
  unsigned short* kb  = qb + nX;
  unsigned short* vb  = kb + nX;
  unsigned short* WqT = vb + nX;        // 3 contiguous = B[3072,1024]
  unsigned short* Qb  = WqT + 3 * nW;
  unsigned short* Kb  = Qb + nX;
  unsigned short* Vt  = Kb + nX;        // [B, DV, S] written directly by QKV epilogue
  unsigned short* U   = (unsigned short*)ws;      // bf16 [B,S,S] overlay (qb+kb dead)
  float*          rowsumP = (float*)vb;           // fp32 [32][B*S] overlay (vb dead)
  float*          P   = (float*)Qb;               // fp32 [B,S,DV] overlay (Qb/Kb dead after scores)

  dim3 blk(256), blk5(512);

  // 1) prep: q/k/v -> bf16 and W -> W^T bf16, one dispatch
  {
    dim3 g(12288 + 3072);
    prep<<<g, blk, 0, stream>>>(q_in, k_in, v_in, Wq, Wk, Wv, qb, WqT);
  }
  // 2) fused QKV projection; V stored transposed into Vt.
  //    BM=128 tiles: grid 12x64 = 768 blocks = EXACTLY 3 full rounds at 1 block/CU
  //    (r16 fix: 384-block BM=256 grid was 2 rounds with the second half-empty).
  {
    dim3 g(3 * DK_ / 256, (B_ * S_) / 128, 1);
    gemm_bt256<unsigned short, 3, 0, 1, 128><<<g, blk5, 0, stream>>>(
        qb, kb, vb, WqT, Qb, Kb, Vt, bq, bk, bv, nullptr,
        DK_, D_, D_, D_, 0, 0, 0, 1.f);
  }
  // 3) U = exp(Q K^T / 32) -> bf16, + 32 partial row sums.  grid 8x8x4 = 256 blocks (1/CU)
  {
    dim3 g(S_ / 256, S_ / 256, B_);
    gemm_bt256<unsigned short, 1, 1, 1, 256><<<g, blk5, 0, stream>>>(
        Qb, nullptr, nullptr, Kb, U, nullptr, nullptr, nullptr, nullptr, nullptr, rowsumP,
        S_, DK_, DK_, DK_, (long)S_ * DK_, (long)S_ * DK_, (long)S_ * S_, 0.03125f);
  }
  // 4) PV split-K=2, plain stores: half0 -> out, half1 -> P.  grid 4x8x8 = 256 blocks (1/CU)
  {
    dim3 g(DV_ / 256, S_ / 256, B_ * 2);
    gemm_bt256<float, 1, 0, 2, 256><<<g, blk5, 0, stream>>>(
        U, nullptr, nullptr, Vt, out, P, nullptr, nullptr, nullptr, nullptr, nullptr,
        DV_, S_ / 2, S_, S_, (long)S_ * S_, (long)DV_ * S_, (long)S_ * DV_, 1.f);
  }
  // 5) out = (out + P) / rowsum; rowsum reduced from the 32 partials in-kernel.
  {
    dim3 g(B_ * S_);
    combine<<<g, blk, 0, stream>>>(out, P, rowsumP);
  }
}

// Round 11
// 336.258 us; speedup vs baseline: 1.0246x; 1.0246x over previous
//
#include <hip/hip_runtime.h>
#include <stdint.h>

// Problem constants (B,S,D fixed by the reference)
#define B_  4
#define S_  2048
#define D_  1024
#define DK_ 1024
#define DV_ 1024

typedef __attribute__((ext_vector_type(8)))  short short8;    // 8 bf16 = 4 VGPRs (MFMA A/B frag)
typedef __attribute__((ext_vector_type(16))) float floatx16;  // 32x32 MFMA C/D frag

// async global->LDS DMA, 16B per lane, wave-uniform LDS base (lane scatters +lane*16B)
#define ASYNC16(gsrc, ldst)                                                        \
  __builtin_amdgcn_global_load_lds(                                                \
      (const __attribute__((address_space(1))) unsigned int*)(gsrc),               \
      (__attribute__((address_space(3))) unsigned int*)(ldst), 16, 0, 0)

#define WAITVM(N) asm volatile("s_waitcnt vmcnt(" #N ")" ::: "memory")

// round-to-nearest-even fp32 -> bf16
__device__ __forceinline__ unsigned short f2bf(float f) {
  union { float f; uint32_t u; } v; v.f = f;
  uint32_t r = v.u + 0x7fffu + ((v.u >> 16) & 1u);
  return (unsigned short)(r >> 16);
}

// ---------------- prep: fp32->bf16 for q/k/v  +  W^T (bf16), one dispatch ----------------
__global__ __launch_bounds__(256)
void prep(const float* __restrict__ q, const float* __restrict__ k, const float* __restrict__ v,
          const float* __restrict__ W0, const float* __restrict__ W1, const float* __restrict__ W2,
          unsigned short* __restrict__ qkv, unsigned short* __restrict__ WT) {
  const int bid = blockIdx.x, tid = threadIdx.x;
  if (bid < 12288) {
    const int t  = bid >> 12;         // tensor 0..2
    const int cb = bid & 4095;        // chunk within tensor
    const float* in = (t == 0) ? q : (t == 1) ? k : v;
    unsigned short* o = qkv + (long)t * ((long)B_ * S_ * D_);
    const int i0 = cb * 512 + tid;    // float4 index (512 per block)
    float4 v0 = ((const float4*)in)[i0];
    float4 v1 = ((const float4*)in)[i0 + 256];
    ushort4 u0, u1;
    u0.x = f2bf(v0.x); u0.y = f2bf(v0.y); u0.z = f2bf(v0.z); u0.w = f2bf(v0.w);
    u1.x = f2bf(v1.x); u1.y = f2bf(v1.y); u1.z = f2bf(v1.z); u1.w = f2bf(v1.w);
    ((ushort4*)o)[i0] = u0;
    ((ushort4*)o)[i0 + 256] = u1;
  } else {
    const int b2 = bid - 12288;
    const int w  = b2 >> 10;          // weight 0..2
    const int tl = b2 & 1023;         // 32x32 tile id
    const float* in = (w == 0) ? W0 : (w == 1) ? W1 : W2;
    unsigned short* o = WT + (long)w * D_ * DK_;
    __shared__ float tile[32][33];
    const int bx = (tl & 31) * 32, by = (tl >> 5) * 32;
    const int tx = tid & 31, ty = tid >> 5;
    for (int r = ty; r < 32; r += 8)
      tile[r][tx] = in[(long)(by + r) * DK_ + bx + tx];
    __syncthreads();
    for (int r = ty; r < 32; r += 8)
      o[(long)(bx + r) * D_ + by + tx] = f2bf(tile[tx][r]);
  }
}

__device__ __forceinline__ void storeC(float* p, float v)          { *p = v; }
__device__ __forceinline__ void storeC(unsigned short* p, float v) { *p = f2bf(v); }

// ---------------- combine: out = (out + P) / rowsum, rowsum = sum of 32 partials ----------------
__global__ __launch_bounds__(256)
void combine(float* __restrict__ out, const float* __restrict__ P,
             const float* __restrict__ rsp) {
  __shared__ float sinv;
  const int row = blockIdx.x;
  const int tid = threadIdx.x;
  if (tid < 32) {
    float s = rsp[(long)tid * (B_ * S_) + row];
#pragma unroll
    for (int m = 1; m < 32; m <<= 1) s += __shfl_xor(s, m, 64);
    if (tid == 0) sinv = 1.0f / s;
  }
  __syncthreads();
  const float inv = sinv;
  const long k = (long)row * 256 + tid;          // float4 index (row covers DV_=1024 floats)
  float4 a = ((const float4*)out)[k];
  float4 b = ((const float4*)P)[k];
  float4 o;
  o.x = (a.x + b.x) * inv; o.y = (a.y + b.y) * inv;
  o.z = (a.z + b.z) * inv; o.w = (a.w + b.w) * inv;
  ((float4*)out)[k] = o;
}

// ---------------- bf16 BT GEMM, BMx256 tile, 8 waves, 4-buf ring, ONE barrier per tile ----------------
// ROUND 17.  r10 post-mortem: (a) BM=128 QKV regressed (per-tile overhead constant, FETCH
//   +24MB) -> QKV reverted to BM=256.  (b) Cross-round budget: QKV ~600 TF, scores/PV ~400 TF
//   in EVERY structure; r5's full PV counters (MfmaUtil 15.4, VALUBusy 6.9, FETCH 24.7MB
//   L2-hot, latency excluded by r9 depth-3 null) leave one suspect: 4 barriers/tile lockstep
//   waves so LDS-port time (reads 96KB + DMA-writes 32KB ~ 500cy/CU/tile) SERIALIZES with
//   MFMA (256cy) instead of overlapping -- and 128 barrier reconvergences/block.
// Barrier audit: ring invariant needs ONE barrier/tile (tail): tile t reads buf t%4; DMAs
//   write (t+3)%4 != t%4 (4-ring, disjoint); publish of t+1 = own-WAITVM(8) then rendezvous;
//   waves drift at most one tile so no wave can overwrite a buffer another is reading.
//   Pre-MFMA barriers + inline lgkmcnt(0) deleted: compiler emits per-MFMA counted lgkm
//   waits (m97 "near-optimal"), so early MFMAs start while later frags are in flight, and
//   different waves' ds_read / DMA / MFMA phases free-run within the tile.
// Per tile: {12 ds_read_b128; stage t+3 (4 DMA); 16 MFMA (setprio 1); WAITVM(8/4/0);
//   s_barrier; compiler memory fence}.  vmcnt never 0 while staging (T4).
// Swizzle (r6-verified): LDS[row][q16] = global[row][q16 ^ ((row>>1)&3)] within 64B line;
//   read off=((s*2+hi)^((lm>>1)&3))*8.  A/B frag (32x32x16): m(n)=lane&31, k-chunk=s*2+hi.
// C/D (m74/m101 verified): col=lane&31, row=(reg&3)+8*(reg>>2)+4*(lane>>5).
// NOUT=3: fused QKV (n0g selects A/C/bias).  sel==2 stores V transposed into Vt[B][DV][S].
// MODE: 0 plain store (+bias if non-null); 1 store exp(val*scale) + partial row sums to rsp.
// KSPL: K-split; kh=bzi&1 selects K-half; kh==1 redirects C to C1 (separate partial buffer).
template <typename OutT, int NOUT, int MODE, int KSPL, int BM>
__global__ __launch_bounds__(512, 2)
void gemm_bt256(const unsigned short* __restrict__ A0, const unsigned short* __restrict__ A1,
                const unsigned short* __restrict__ A2, const unsigned short* __restrict__ Bm,
                OutT* __restrict__ C0, OutT* __restrict__ C1, OutT* __restrict__ C2,
                const float* __restrict__ b0, const float* __restrict__ b1,
                const float* __restrict__ b2, float* __restrict__ rsp,
                int N, int K, int lda, int ldb, long sA, long sB, long sC, float scale) {
  constexpr int IR = BM / 64;          // acc row-frags per wave (256->4, 128->2)
  constexpr int nA = BM / 128;         // A DMAs per wave per tile (2 or 1)
  __shared__ __align__(16) unsigned short As[4][BM * 32];    // 4-ring (256: 64KB)
  __shared__ __align__(16) unsigned short Bs[4][256 * 32];   // 64KB
  const int tid  = threadIdx.x;
  const int lane = tid & 63, wave = tid >> 6;     // 8 waves
  const int wm = (wave >> 2) * (BM / 2);          // 2 M-waves
  const int wn = (wave & 3) * 64;                 // 4 N-waves
  const int lm = lane & 31;
  const int hi = lane >> 5;

  // ---- bijective XCD-chunk remap (8 XCDs; every grid here has total %8 == 0) ----
  const int gx = gridDim.x, gy = gridDim.y;
  const int T  = gx * gy * (int)gridDim.z;
  const int l  = blockIdx.x + gx * (blockIdx.y + gy * blockIdx.z);
  const int l2 = (l & 7) * (T >> 3) + (l >> 3);
  const int bxi = l2 % gx;
  const int byi = (l2 / gx) % gy;
  const int bzi = l2 / (gx * gy);

  const int  kh = (KSPL > 1) ? (bzi & (KSPL - 1)) : 0;
  const long zb = (KSPL > 1) ? (bzi >> 1) : bzi;
  const int m0  = byi * BM;
  const int n0g = bxi * 256;

  const unsigned short* A = A0;
  OutT* C = C0;
  const float* bias = b0;
  int n0 = n0g, sel = 0;
  if (NOUT == 3) {
    sel = n0g >> 10;
    n0 = n0g & 1023;
    if (sel == 1)      { A = A1; C = C1; bias = b1; }
    else if (sel == 2) { A = A2; C = C2; bias = b2; }
  }
  if (KSPL > 1 && kh) C = C1;          // K-half 1 writes its own partial buffer
  A += zb * sA + (long)kh * K;
  const unsigned short* Bp = Bm + zb * sB + (long)kh * K;
  C += zb * sC;

  // ---- staging: wave w owns A rows [BM/8*w, +BM/8), B rows [32w, 32w+32) ----
  const int rr = lane >> 2;
  const int cc = (((lane & 3) ^ ((lane >> 3) & 3)) * 8);    // 64B-line XOR swizzle on source
  const unsigned short* gA0 = A  + (long)(m0  + (BM / 8) * wave + rr) * lda + cc;
  const unsigned short* gA1 = gA0 + 16 * (long)lda;          // used only if nA==2
  const unsigned short* gB0 = Bp + (long)(n0g + 32 * wave + rr) * ldb + cc;
  const unsigned short* gB1 = gB0 + 16 * (long)ldb;
  const int aoff = wave * (BM * 4);                          // (BM/8)*32 shorts per wave
  const int boff = wave * 1024;

  floatx16 acc[IR][2] = {};
  const int sw = (lm >> 1) & 3;

  const int nt = K >> 5;                           // BK=32 tiles (>= 4 for all our shapes)

  // ---- prologue: stage tiles 0,1,2 -> bufs 0,1,2; retire tile 0's DMAs ----
#pragma unroll
  for (int pt = 0; pt < 3; pt++) {
    ASYNC16(gA0, &As[pt][aoff]);
    if (nA == 2) ASYNC16(gA1, &As[pt][aoff + 512]);
    ASYNC16(gB0, &Bs[pt][boff]); ASYNC16(gB1, &Bs[pt][boff + 512]);
    gA0 += 32; gA1 += 32; gB0 += 32; gB1 += 32;
  }
  if constexpr (BM == 256) { WAITVM(8); } else { WAITVM(6); }
  __builtin_amdgcn_s_barrier();
  asm volatile("" ::: "memory");

  // ---- main loop: ONE barrier per BK=32 tile, 4-buf ring, depth-3 lookahead ----
  for (int t = 0; t < nt; t++) {
    const int bc = t & 3;                          // buf of tile t
    const int bs = (t + 3) & 3;                    // buf of tile t+3 (ring: != bc)
    const bool pre = (t + 3 < nt);

    // all 12 fragment reads up front; compiler inserts counted lgkm waits per MFMA
    short8 af[IR][2], bf[2][2];
#pragma unroll
    for (int i = 0; i < IR; i++)
#pragma unroll
      for (int s = 0; s < 2; s++)
        af[i][s] = *(const short8*)&As[bc][(wm + i * 32 + lm) * 32 + (((s * 2 + hi) ^ sw) * 8)];
#pragma unroll
    for (int j = 0; j < 2; j++)
#pragma unroll
      for (int s = 0; s < 2; s++)
        bf[j][s] = *(const short8*)&Bs[bc][(wn + j * 32 + lm) * 32 + (((s * 2 + hi) ^ sw) * 8)];

    if (pre) {
      ASYNC16(gA0, &As[bs][aoff]);
      if (nA == 2) ASYNC16(gA1, &As[bs][aoff + 512]);
      ASYNC16(gB0, &Bs[bs][boff]); ASYNC16(gB1, &Bs[bs][boff + 512]);
      gA0 += 32; gA1 += 32; gB0 += 32; gB1 += 32;
    }

    __builtin_amdgcn_s_setprio(1);
#pragma unroll
    for (int s = 0; s < 2; s++)
#pragma unroll
      for (int i = 0; i < IR; i++)
#pragma unroll
        for (int j = 0; j < 2; j++)
          acc[i][j] = __builtin_amdgcn_mfma_f32_32x32x16_bf16(af[i][s], bf[j][s], acc[i][j], 0, 0, 0);
    __builtin_amdgcn_s_setprio(0);

    // retire tile t+1's DMAs (publish), keep t+2/t+3 in flight; single rendezvous
    if (t + 3 < nt)      { if constexpr (BM == 256) { WAITVM(8); } else { WAITVM(6); } }
    else if (t + 2 < nt) { if constexpr (BM == 256) { WAITVM(4); } else { WAITVM(3); } }
    else                 { WAITVM(0); }
    __builtin_amdgcn_s_barrier();
    asm volatile("" ::: "memory");
  }

  // ---- epilogue: C/D col=lane&31, row=(r&3)+8*(r>>2)+4*hi ----
  if (NOUT == 3 && sel == 2) {
    // V output, stored transposed into Vt[B][DV][S]
    unsigned short* Vt = (unsigned short*)C;
    const int b = m0 >> 11;              // batch (2048 rows per batch; BM | 2048)
    const int sbase = (m0 & 2047);
#pragma unroll
    for (int i = 0; i < IR; i++) {
      const int srowb = sbase + wm + i * 32 + (hi << 2);
#pragma unroll
      for (int j = 0; j < 2; j++) {
        const int col = n0 + wn + j * 32 + lm;
        const float bv = bias[col];
        unsigned short* vp = Vt + ((long)b * DV_ + col) * S_ + srowb;
#pragma unroll
        for (int g = 0; g < 4; g++) {
          ushort4 u;
          u.x = f2bf(acc[i][j][4 * g + 0] + bv);
          u.y = f2bf(acc[i][j][4 * g + 1] + bv);
          u.z = f2bf(acc[i][j][4 * g + 2] + bv);
          u.w = f2bf(acc[i][j][4 * g + 3] + bv);
          *(ushort4*)(vp + 8 * g) = u;
        }
      }
    }
  } else if (MODE == 1) {
    // scores: store U = exp(score*scale); per-(bxi,wave) partial row sums -> rsp (plain stores)
#pragma unroll
    for (int i = 0; i < IR; i++) {
#pragma unroll
      for (int r = 0; r < 16; r++) {
        const int row = m0 + wm + i * 32 + (r & 3) + ((r >> 2) << 3) + (hi << 2);
        float sum2 = 0.f;
#pragma unroll
        for (int j = 0; j < 2; j++) {
          const int col = n0 + wn + j * 32 + lm;
          float e = __expf(acc[i][j][r] * scale);
          storeC(C + (long)row * N + col, e);
          sum2 += e;
        }
#pragma unroll
        for (int msk = 1; msk < 32; msk <<= 1) sum2 += __shfl_xor(sum2, msk, 64);
        if ((lane & 31) == 0)
          rsp[(long)(bxi * 4 + (wave & 3)) * (B_ * S_) + zb * S_ + row] = sum2;
      }
    }
  } else {
#pragma unroll
    for (int i = 0; i < IR; i++) {
#pragma unroll
      for (int j = 0; j < 2; j++) {
        const int col = n0 + wn + j * 32 + lm;
        const float bv = bias ? bias[col] : 0.f;
#pragma unroll
        for (int r = 0; r < 16; r++) {
          const int rl = wm + i * 32 + (r & 3) + ((r >> 2) << 3) + (hi << 2);
          storeC(C + (long)(m0 + rl) * N + col, acc[i][j][r] * scale + bv);
        }
      }
    }
  }
}

extern "C" void kernel_launch(void* const* d_in, const int* in_sizes, int n_in,
                              void* d_out, int out_size, void* d_ws, size_t ws_size,
                              hipStream_t stream) {
  const float* q_in = (const float*)d_in[0];
  const float* k_in = (const float*)d_in[1];
  const float* v_in = (const float*)d_in[2];
  const float* Wq   = (const float*)d_in[3];
  const float* bq   = (const float*)d_in[4];
  const float* Wk   = (const float*)d_in[5];
  const float* bk   = (const float*)d_in[6];
  const float* Wv   = (const float*)d_in[7];
  const float* bv   = (const float*)d_in[8];
  float* out = (float*)d_out;

  // ---- workspace layout ----
  // U (bf16 scores, 33.5MB) overlays dead qb+kb after QKV;
  // rowsumP (32 x B*S fp32 = 1MB) overlays dead vb after QKV;
  // P (fp32 PV half-1 partial, 33.5MB) overlays dead Qb+Kb after scores.
  char* ws = (char*)d_ws;
  const long nX = (long)B_ * S_ * D_;   // 8388608 elems
  const long nW = (long)D_ * DK_;       // 1048576
  unsigned short* qb  = (unsigned short*)(ws);
  unsigned short* kb  = qb + nX;
  unsigned short* vb  = kb + nX;
  unsigned short* WqT = vb + nX;        // 3 contiguous = B[3072,1024]
  unsigned short* Qb  = WqT + 3 * nW;
  unsigned short* Kb  = Qb + nX;
  unsigned short* Vt  = Kb + nX;        // [B, DV, S] written directly by QKV epilogue
  unsigned short* U   = (unsigned short*)ws;      // bf16 [B,S,S] overlay (qb+kb dead)
  float*          rowsumP = (float*)vb;           // fp32 [32][B*S] overlay (vb dead)
  float*          P   = (float*)Qb;               // fp32 [B,S,DV] overlay (Qb/Kb dead after scores)

  dim3 blk(256), blk5(512);

  // 1) prep: q/k/v -> bf16 and W -> W^T bf16, one dispatch
  {
    dim3 g(12288 + 3072);
    prep<<<g, blk, 0, stream>>>(q_in, k_in, v_in, Wq, Wk, Wv, qb, WqT);
  }
  // 2) fused QKV projection; V stored transposed into Vt.  BM=256 (r10: BM=128 regressed);
  //    grid 12x32 = 384 blocks.
  {
    dim3 g(3 * DK_ / 256, (B_ * S_) / 256, 1);
    gemm_bt256<unsigned short, 3, 0, 1, 256><<<g, blk5, 0, stream>>>(
        qb, kb, vb, WqT, Qb, Kb, Vt, bq, bk, bv, nullptr,
        DK_, D_, D_, D_, 0, 0, 0, 1.f);
  }
  // 3) U = exp(Q K^T / 32) -> bf16, + 32 partial row sums.  grid 8x8x4 = 256 blocks (1/CU)
  {
    dim3 g(S_ / 256, S_ / 256, B_);
    gemm_bt256<unsigned short, 1, 1, 1, 256><<<g, blk5, 0, stream>>>(
        Qb, nullptr, nullptr, Kb, U, nullptr, nullptr, nullptr, nullptr, nullptr, rowsumP,
        S_, DK_, DK_, DK_, (long)S_ * DK_, (long)S_ * DK_, (long)S_ * S_, 0.03125f);
  }
  // 4) PV split-K=2, plain stores: half0 -> out, half1 -> P.  grid 4x8x8 = 256 blocks (1/CU)
  {
    dim3 g(DV_ / 256, S_ / 256, B_ * 2);
    gemm_bt256<float, 1, 0, 2, 256><<<g, blk5, 0, stream>>>(
        U, nullptr, nullptr, Vt, out, P, nullptr, nullptr, nullptr, nullptr, nullptr,
        DV_, S_ / 2, S_, S_, (long)S_ * S_, (long)DV_ * S_, (long)S_ * DV_, 1.f);
  }
  // 5) out = (out + P) / rowsum; rowsum reduced from the 32 partials in-kernel.
  {
    dim3 g(B_ * S_);
    combine<<<g, blk, 0, stream>>>(out, P, rowsumP);
  }
}